// Round 8
// baseline (184.341 us; speedup 1.0000x reference)
//
#include <hip/hip_runtime.h>
#include <hip/hip_bf16.h>

typedef __bf16 bf16;
typedef bf16 bf16x8 __attribute__((ext_vector_type(8)));
typedef bf16 bf16x4v __attribute__((ext_vector_type(4)));
typedef _Float16 f16;
typedef f16 f16x4 __attribute__((ext_vector_type(4)));
typedef float f32x4 __attribute__((ext_vector_type(4)));

constexpr int LL = 1024;   // sequence length
constexpr int EE = 512;    // embed dim
constexpr int NBATCH = 8;

__device__ __forceinline__ f32x4 mfma16(bf16x8 a, bf16x8 b, f32x4 c) {
    return __builtin_amdgcn_mfma_f32_16x16x32_bf16(a, b, c, 0, 0, 0);
}

// global -> LDS direct DMA, 16B per lane; LDS dest = wave-uniform base + lane*16.
#define GLOAD_LDS16(g, l)                                                     \
    __builtin_amdgcn_global_load_lds(                                         \
        (const __attribute__((address_space(1))) void*)(g),                   \
        (__attribute__((address_space(3))) void*)(l), 16, 0, 0)

// ---------------------------------------------------------------------------
// fp32 -> bf16 conversion for modalA, modalB, and the 4 weight matrices.
// ---------------------------------------------------------------------------
struct CvtParams {
    const float* src[6];
    bf16* dst[6];
    int n4[6];  // element count / 4
};

__global__ __launch_bounds__(256) void cvt_kernel(CvtParams p) {
    const int y = blockIdx.y;
    const float* __restrict__ src = p.src[y];
    bf16* __restrict__ dst = p.dst[y];
    const int n4 = p.n4[y];
    for (int i = blockIdx.x * 256 + threadIdx.x; i < n4; i += gridDim.x * 256) {
        float4 v = *(const float4*)(src + (size_t)i * 4);
        bf16x4v o;
        o[0] = (bf16)v.x; o[1] = (bf16)v.y; o[2] = (bf16)v.z; o[3] = (bf16)v.w;
        *(bf16x4v*)(dst + (size_t)i * 4) = o;
    }
}

// ---------------------------------------------------------------------------
// Projection: O[z] = bf16( X[z] @ W[z]^T + b[z] ), bf16 NT GEMM, 128x256 tile
// (unchanged from R6).
// ---------------------------------------------------------------------------
struct ProjParams {
    const bf16* x[4];
    const bf16* w[4];
    const float* b[4];
};

__global__ __launch_bounds__(256, 2) void proj_kernel(ProjParams p, bf16* __restrict__ outbase) {
    const int f = blockIdx.x;
    const int z = f >> 7;
    const int j = f & 127;
    const int bxp = j & 1, by = j >> 1;

    const bf16* __restrict__ X = p.x[z];
    const bf16* __restrict__ W = p.w[z];
    const float* __restrict__ Bv = p.b[z];
    bf16* __restrict__ O = outbase + (size_t)z * (NBATCH * LL) * EE;

    __shared__ union {
        struct { alignas(16) bf16 A[2][128][32]; alignas(16) bf16 B[2][256][32]; } st;
        alignas(16) bf16 ep[64][264];  // stride 264 (132 words ≡ 4 mod 32): balanced
    } sm;

    const int t = threadIdx.x;
    const int lane = t & 63, wid = t >> 6;
    const int wm = wid & 1, wn = wid >> 1;
    const int lr = lane & 15, kg = lane >> 4;

    f32x4 acc[4][8] = {};

    const int srow = t >> 2;
    const int cgl = t & 3;
    const int gcg = (cgl ^ ((srow >> 1) & 3)) * 8;
    const int scg = (kg ^ ((lr >> 1) & 3)) * 8;

    const bf16* Xrow0 = X + (size_t)(by * 128 + srow) * EE + gcg;
    const bf16* Wrow0 = W + (size_t)(bxp * 256 + srow) * EE + gcg;

    auto stage = [&](int k, int b) {
        const int k0 = k * 32;
#pragma unroll
        for (int i = 0; i < 2; ++i)
            GLOAD_LDS16(Xrow0 + (size_t)(64 * i) * EE + k0, &sm.st.A[b][srow + 64 * i][cgl * 8]);
#pragma unroll
        for (int i = 0; i < 4; ++i)
            GLOAD_LDS16(Wrow0 + (size_t)(64 * i) * EE + k0, &sm.st.B[b][srow + 64 * i][cgl * 8]);
    };
    auto compute = [&](int b) {
        bf16x8 af[4], bfr[8];
#pragma unroll
        for (int im = 0; im < 4; ++im)
            af[im] = *(const bf16x8*)&sm.st.A[b][wm * 64 + im * 16 + lr][scg];
#pragma unroll
        for (int in = 0; in < 8; ++in)
            bfr[in] = *(const bf16x8*)&sm.st.B[b][wn * 128 + in * 16 + lr][scg];
#pragma unroll
        for (int im = 0; im < 4; ++im)
#pragma unroll
            for (int in = 0; in < 8; ++in)
                acc[im][in] = mfma16(af[im], bfr[in], acc[im][in]);
    };

    stage(0, 0);
#pragma unroll
    for (int k = 0; k < 16; ++k) {
        __builtin_amdgcn_s_waitcnt(0);
        __syncthreads();
        if (k < 15) stage(k + 1, (k + 1) & 1);
        compute(k & 1);
    }
    __syncthreads();

    // C/D layout (16x16x32): col = lane&15, row = (lane>>4)*4 + reg  [m89]
#pragma unroll
    for (int pph = 0; pph < 2; ++pph) {
        if (wm == pph) {
#pragma unroll
            for (int im = 0; im < 4; ++im) {
                const int row = im * 16 + kg * 4;
#pragma unroll
                for (int in = 0; in < 8; ++in) {
                    const int col = wn * 128 + in * 16 + lr;
                    const float bias = Bv[bxp * 256 + col];
#pragma unroll
                    for (int r = 0; r < 4; ++r)
                        sm.ep[row + r][col] = (bf16)(acc[im][in][r] + bias);
                }
            }
        }
        __syncthreads();
#pragma unroll
        for (int i = 0; i < 8; ++i) {
            const int c = i * 256 + t;
            const int row = c >> 5, colg = (c & 31) * 8;
            *(uint4*)(O + (size_t)(by * 128 + pph * 64 + row) * EE + bxp * 256 + colg) =
                *(const uint4*)&sm.ep[row][colg];
        }
        __syncthreads();
    }
}

// ---------------------------------------------------------------------------
// Scores: S[m][n] = f16( (Q[m][n] @ K[m][n]^T) * inv_scale ).
// 256x256 block tile, 4 waves each owning 128x128 (acc[8][8] = 256 AGPRs,
// launch_bounds(256,1) -> 1 block/CU). 64 FLOP/LDS-read-byte.
// Grid 512 = 32 slices x 16 tiles (4x4 of 256) = 2 blocks/CU, no tail.
// XCD swizzle: f&7 owns 4 (map,batch) slices.
// ---------------------------------------------------------------------------
struct ScoresParams {
    const bf16* q[4];
    const bf16* k[4];
    f16* s[4];
};

__global__ __launch_bounds__(256, 1) void scores_kernel(ScoresParams p) {
    const int f = blockIdx.x;         // 512 blocks
    const int xcd = f & 7;
    const int j = f >> 3;             // 0..63 per XCD
    const int z = (xcd << 2) + (j >> 4);   // 4 slices per XCD
    const int map = z >> 3, n = z & 7;
    const int tile = j & 15;          // 16 tiles per slice: 4 row x 4 col
    const int bxp = tile & 3, by = tile >> 2;

    const bf16* __restrict__ Qb = p.q[map] + (size_t)n * LL * EE;
    const bf16* __restrict__ Kb = p.k[map] + (size_t)n * LL * EE;
    f16* __restrict__ Sb = p.s[map] + (size_t)n * LL * LL;

    __shared__ union {
        struct { alignas(16) bf16 A[2][256][32]; alignas(16) bf16 B[2][256][32]; } st;
        alignas(16) f16 ep[64][264];
    } sm;

    const int t = threadIdx.x;
    const int lane = t & 63, wid = t >> 6;
    const int wm = wid & 1, wn = wid >> 1;
    const int lr = lane & 15, kg = lane >> 4;

    f32x4 acc[8][8] = {};   // 256 AGPRs/wave

    const int srow = t >> 2;          // 0..63
    const int cgl = t & 3;
    const int gcg = (cgl ^ ((srow >> 1) & 3)) * 8;  // swizzled global col-group
    const int scg = (kg ^ ((lr >> 1) & 3)) * 8;     // swizzled LDS read col-group

    const bf16* Qrow0 = Qb + (size_t)(by * 256 + srow) * EE + gcg;
    const bf16* Krow0 = Kb + (size_t)(bxp * 256 + srow) * EE + gcg;

    auto stage = [&](int k, int b) {
        const int k0 = k * 32;
#pragma unroll
        for (int i = 0; i < 4; ++i) {
            GLOAD_LDS16(Qrow0 + (size_t)(64 * i) * EE + k0, &sm.st.A[b][srow + 64 * i][cgl * 8]);
            GLOAD_LDS16(Krow0 + (size_t)(64 * i) * EE + k0, &sm.st.B[b][srow + 64 * i][cgl * 8]);
        }
    };
    auto compute = [&](int b) {
        bf16x8 af[8], bfr[8];
#pragma unroll
        for (int im = 0; im < 8; ++im)
            af[im] = *(const bf16x8*)&sm.st.A[b][wm * 128 + im * 16 + lr][scg];
#pragma unroll
        for (int in = 0; in < 8; ++in)
            bfr[in] = *(const bf16x8*)&sm.st.B[b][wn * 128 + in * 16 + lr][scg];
#pragma unroll
        for (int im = 0; im < 8; ++im)
#pragma unroll
            for (int in = 0; in < 8; ++in)
                acc[im][in] = mfma16(af[im], bfr[in], acc[im][in]);
    };

    stage(0, 0);
#pragma unroll
    for (int k = 0; k < 16; ++k) {
        __builtin_amdgcn_s_waitcnt(0);
        __syncthreads();
        if (k < 15) stage(k + 1, (k + 1) & 1);
        compute(k & 1);
    }
    __syncthreads();

    const float inv_scale = 0.011048543456039806f;  // 1/(4*sqrt(512))
    // Epilogue: 4 phases of 64 rows. Global row = by*256 + wm*128 + im*16 +
    // kg*4 + r; phase ph covers wm = ph>>1, im-half = ph&1.
#pragma unroll
    for (int ph = 0; ph < 4; ++ph) {
        const int pwm = ph >> 1, pih = ph & 1;
        if (wm == pwm) {
#pragma unroll
            for (int imm = 0; imm < 4; ++imm) {
                const int im = pih * 4 + imm;
                const int row = imm * 16 + kg * 4;
#pragma unroll
                for (int in = 0; in < 8; ++in) {
                    const int col = wn * 128 + in * 16 + lr;
#pragma unroll
                    for (int r = 0; r < 4; ++r)
                        sm.ep[row + r][col] = (f16)(acc[im][in][r] * inv_scale);
                }
            }
        }
        __syncthreads();
#pragma unroll
        for (int i = 0; i < 8; ++i) {
            const int c = i * 256 + t;
            const int row = c >> 5, colg = (c & 31) * 8;
            *(uint4*)(Sb + (size_t)(by * 256 + ph * 64 + row) * LL + bxp * 256 + colg) =
                *(const uint4*)&sm.ep[row][colg];
        }
        __syncthreads();
    }
}

// ---------------------------------------------------------------------------
// Row softmax (1024 cols, f16 in) over 8 batches, mean, write one quadrant.
// No max-subtraction: |S| small (sigma ~0.25), exp is exact-safe in fp32.
// grid (1024, 4): x = q row, y = map.
// ---------------------------------------------------------------------------
struct SmParams {
    const f16* s[4];
};

__global__ __launch_bounds__(256) void softmax_mean_kernel(SmParams p, float* __restrict__ out) {
    const int q = blockIdx.x;
    const int map = blockIdx.y;
    const f16* __restrict__ S = p.s[map];
    const int t = threadIdx.x;
    const int lane = t & 63, wid = t >> 6;
    __shared__ float red[NBATCH][4];

    f16x4 v[NBATCH];
#pragma unroll
    for (int n = 0; n < NBATCH; ++n)
        v[n] = *(const f16x4*)(S + ((size_t)n * LL + q) * LL + t * 4);

    float e[NBATCH][4];
#pragma unroll
    for (int n = 0; n < NBATCH; ++n) {
        float s = 0.f;
#pragma unroll
        for (int j = 0; j < 4; ++j) {
            e[n][j] = __expf((float)v[n][j]);
            s += e[n][j];
        }
#pragma unroll
        for (int off = 32; off; off >>= 1) s += __shfl_xor(s, off);
        if (lane == 0) red[n][wid] = s;
    }
    __syncthreads();

    float acc[4] = {};
#pragma unroll
    for (int n = 0; n < NBATCH; ++n) {
        const float inv = 1.0f / (red[n][0] + red[n][1] + red[n][2] + red[n][3]);
#pragma unroll
        for (int j = 0; j < 4; ++j) acc[j] += e[n][j] * inv;
    }

    const int orow = (map >= 2 ? LL : 0) + q;
    const int ocol = (map & 1 ? LL : 0) + t * 4;
    float4 o = make_float4(acc[0] * 0.125f, acc[1] * 0.125f, acc[2] * 0.125f, acc[3] * 0.125f);
    *(float4*)(out + (size_t)orow * (2 * LL) + ocol) = o;
}

// ---------------------------------------------------------------------------
extern "C" void kernel_launch(void* const* d_in, const int* in_sizes, int n_in,
                              void* d_out, int out_size, void* d_ws, size_t ws_size,
                              hipStream_t stream) {
    const float* modalA = (const float*)d_in[0];
    const float* modalB = (const float*)d_in[1];
    const float* WqA = (const float*)d_in[2];
    const float* bqA = (const float*)d_in[3];
    const float* WkA = (const float*)d_in[4];
    const float* bkA = (const float*)d_in[5];
    const float* WqB = (const float*)d_in[6];
    const float* bqB = (const float*)d_in[7];
    const float* WkB = (const float*)d_in[8];
    const float* bkB = (const float*)d_in[9];
    float* out = (float*)d_out;

    // ws layout (~100.7 MB):
    //   [qk: 4 x 8192x512 bf16 = 33.55 MB]
    //   [region2: XA/XB/W4 bf16 (18.9 MB) then reused by S[4] f16 (67.1 MB)]
    const size_t projN = (size_t)(NBATCH * LL) * EE;       // 4 Mi elems
    const size_t mapN = (size_t)NBATCH * LL * LL;          // 8 Mi elems per map
    char* base = (char*)d_ws;
    bf16* qk = (bf16*)base;
    char* region2 = base + 4 * projN * sizeof(bf16);
    bf16* XA = (bf16*)region2;
    bf16* XB = XA + projN;
    bf16* W4 = XB + projN;                                  // 4 x 512x512
    f16* S = (f16*)region2;

    CvtParams cp;
    cp.src[0] = modalA; cp.dst[0] = XA; cp.n4[0] = (int)(projN / 4);
    cp.src[1] = modalB; cp.dst[1] = XB; cp.n4[1] = (int)(projN / 4);
    const float* wsrc[4] = {WqA, WkA, WqB, WkB};
    for (int i = 0; i < 4; ++i) {
        cp.src[2 + i] = wsrc[i];
        cp.dst[2 + i] = W4 + (size_t)i * EE * EE;
        cp.n4[2 + i] = EE * EE / 4;
    }
    cvt_kernel<<<dim3(512, 6), 256, 0, stream>>>(cp);

    ProjParams pp;
    pp.x[0] = XA; pp.x[1] = XA; pp.x[2] = XB; pp.x[3] = XB;
    for (int i = 0; i < 4; ++i) pp.w[i] = W4 + (size_t)i * EE * EE;
    pp.b[0] = bqA; pp.b[1] = bkA; pp.b[2] = bqB; pp.b[3] = bkB;
    proj_kernel<<<dim3(512), 256, 0, stream>>>(pp, qk);

    const bf16* qA = qk + 0 * projN;
    const bf16* kA = qk + 1 * projN;
    const bf16* qB = qk + 2 * projN;
    const bf16* kB = qk + 3 * projN;

    // map order: 0=(qA,kA)->TL, 1=(qA,kB)->TR, 2=(qB,kB)->BL, 3=(qB,kA)->BR
    ScoresParams sp;
    sp.q[0] = qA; sp.q[1] = qA; sp.q[2] = qB; sp.q[3] = qB;
    sp.k[0] = kA; sp.k[1] = kB; sp.k[2] = kB; sp.k[3] = kA;
    for (int m = 0; m < 4; ++m) sp.s[m] = S + (size_t)m * mapN;
    scores_kernel<<<dim3(512), 256, 0, stream>>>(sp);

    SmParams smp;
    for (int m = 0; m < 4; ++m) smp.s[m] = S + (size_t)m * mapN;
    softmax_mean_kernel<<<dim3(1024, 4), 256, 0, stream>>>(smp, out);
}

// Round 9
// 176.867 us; speedup vs baseline: 1.0423x; 1.0423x over previous
//
#include <hip/hip_runtime.h>
#include <hip/hip_bf16.h>

typedef __bf16 bf16;
typedef bf16 bf16x8 __attribute__((ext_vector_type(8)));
typedef bf16 bf16x4v __attribute__((ext_vector_type(4)));
typedef _Float16 f16;
typedef f16 f16x4 __attribute__((ext_vector_type(4)));
typedef float f32x4 __attribute__((ext_vector_type(4)));

constexpr int LL = 1024;   // sequence length
constexpr int EE = 512;    // embed dim
constexpr int NBATCH = 8;

__device__ __forceinline__ f32x4 mfma16(bf16x8 a, bf16x8 b, f32x4 c) {
    return __builtin_amdgcn_mfma_f32_16x16x32_bf16(a, b, c, 0, 0, 0);
}

// global -> LDS direct DMA, 16B per lane; LDS dest = wave-uniform base + lane*16.
#define GLOAD_LDS16(g, l)                                                     \
    __builtin_amdgcn_global_load_lds(                                         \
        (const __attribute__((address_space(1))) void*)(g),                   \
        (__attribute__((address_space(3))) void*)(l), 16, 0, 0)

// Raw workgroup barrier WITHOUT the compiler's vmcnt(0) full drain.
// asm memory clobbers stop compiler-level reordering of LDS/global ops.
__device__ __forceinline__ void wave_barrier() {
    __asm__ volatile("" ::: "memory");
    __builtin_amdgcn_s_barrier();
    __asm__ volatile("" ::: "memory");
}

// s_waitcnt immediates (gfx9 encoding): vmcnt[3:0]|[15:14], expcnt[6:4], lgkmcnt[11:8]
constexpr int WAIT_VM6 = 0xF76;  // vmcnt(6), exp/lgkm no-wait
constexpr int WAIT_VM0 = 0xF70;  // vmcnt(0), exp/lgkm no-wait

// ---------------------------------------------------------------------------
// fp32 -> bf16 conversion for modalA, modalB, and the 4 weight matrices.
// ---------------------------------------------------------------------------
struct CvtParams {
    const float* src[6];
    bf16* dst[6];
    int n4[6];  // element count / 4
};

__global__ __launch_bounds__(256) void cvt_kernel(CvtParams p) {
    const int y = blockIdx.y;
    const float* __restrict__ src = p.src[y];
    bf16* __restrict__ dst = p.dst[y];
    const int n4 = p.n4[y];
    for (int i = blockIdx.x * 256 + threadIdx.x; i < n4; i += gridDim.x * 256) {
        float4 v = *(const float4*)(src + (size_t)i * 4);
        bf16x4v o;
        o[0] = (bf16)v.x; o[1] = (bf16)v.y; o[2] = (bf16)v.z; o[3] = (bf16)v.w;
        *(bf16x4v*)(dst + (size_t)i * 4) = o;
    }
}

// ---------------------------------------------------------------------------
// Projection: O[z] = bf16( X[z] @ W[z]^T + b[z] ), bf16 NT GEMM, 128x256 tile.
// XCD swizzle: xcd = f&7; XCDs 0-3 own modality A, 4-7 own B; within an XCD,
// a 16-row-tile band of X (2 MB) is shared by both {q,k} projections and both
// column halves -> per-XCD L2 working set ~2.5 MB, X fetched from HBM once.
// Triple-buffered K-loop: raw s_barrier + vmcnt(6) (only oldest stage waited).
// ---------------------------------------------------------------------------
struct ProjParams {
    const bf16* x[4];
    const bf16* w[4];
    const float* b[4];
};

__global__ __launch_bounds__(256, 2) void proj_kernel(ProjParams p, bf16* __restrict__ outbase) {
    const int f = blockIdx.x;            // 512 blocks
    const int xcd = f & 7;
    const int u = f >> 3;                // 0..63 per XCD
    const int mz = xcd >> 2;             // modality: 0=A, 1=B
    const int by = (xcd & 3) * 16 + (u & 15);   // 0..63 row tile
    const int zq = (u >> 4) & 1;         // q or k projection
    const int bxp = u >> 5;              // 256-col half
    const int z = mz * 2 + zq;

    const bf16* __restrict__ X = p.x[z];
    const bf16* __restrict__ W = p.w[z];
    const float* __restrict__ Bv = p.b[z];
    bf16* __restrict__ O = outbase + (size_t)z * (NBATCH * LL) * EE;

    __shared__ union {
        struct { alignas(16) bf16 A[3][128][32]; alignas(16) bf16 B[3][256][32]; } st;
        alignas(16) bf16 ep[64][264];  // stride 264 (132 words ≡ 4 mod 32): balanced
    } sm;

    const int t = threadIdx.x;
    const int lane = t & 63, wid = t >> 6;
    const int wm = wid & 1, wn = wid >> 1;
    const int lr = lane & 15, kg = lane >> 4;

    f32x4 acc[4][8] = {};

    const int srow = t >> 2;
    const int cgl = t & 3;
    const int gcg = (cgl ^ ((srow >> 1) & 3)) * 8;  // swizzled global col-group
    const int scg = (kg ^ ((lr >> 1) & 3)) * 8;     // swizzled LDS read col-group

    const bf16* Xrow0 = X + (size_t)(by * 128 + srow) * EE + gcg;
    const bf16* Wrow0 = W + (size_t)(bxp * 256 + srow) * EE + gcg;

    auto stage = [&](int k, int b) {
        const int k0 = k * 32;
#pragma unroll
        for (int i = 0; i < 2; ++i)
            GLOAD_LDS16(Xrow0 + (size_t)(64 * i) * EE + k0, &sm.st.A[b][srow + 64 * i][cgl * 8]);
#pragma unroll
        for (int i = 0; i < 4; ++i)
            GLOAD_LDS16(Wrow0 + (size_t)(64 * i) * EE + k0, &sm.st.B[b][srow + 64 * i][cgl * 8]);
    };
    auto compute = [&](int b) {
        bf16x8 af[4], bfr[8];
#pragma unroll
        for (int im = 0; im < 4; ++im)
            af[im] = *(const bf16x8*)&sm.st.A[b][wm * 64 + im * 16 + lr][scg];
#pragma unroll
        for (int in = 0; in < 8; ++in)
            bfr[in] = *(const bf16x8*)&sm.st.B[b][wn * 128 + in * 16 + lr][scg];
#pragma unroll
        for (int im = 0; im < 4; ++im)
#pragma unroll
            for (int in = 0; in < 8; ++in)
                acc[im][in] = mfma16(af[im], bfr[in], acc[im][in]);
    };

    stage(0, 0);
    stage(1, 1);
#pragma unroll
    for (int k = 0; k < 16; ++k) {
        if (k < 15) __builtin_amdgcn_s_waitcnt(WAIT_VM6);  // stage(k) done; stage(k+1) in flight
        else        __builtin_amdgcn_s_waitcnt(WAIT_VM0);  // last: nothing newer outstanding
        wave_barrier();
        if (k < 14) stage(k + 2, (k + 2) % 3);  // buf (k+2)%3 == compute(k-1)'s buf: all past it
        compute(k % 3);
    }
    __syncthreads();

    // C/D layout (16x16x32): col = lane&15, row = (lane>>4)*4 + reg  [m89]
#pragma unroll
    for (int pph = 0; pph < 2; ++pph) {
        if (wm == pph) {
#pragma unroll
            for (int im = 0; im < 4; ++im) {
                const int row = im * 16 + kg * 4;
#pragma unroll
                for (int in = 0; in < 8; ++in) {
                    const int col = wn * 128 + in * 16 + lr;
                    const float bias = Bv[bxp * 256 + col];
#pragma unroll
                    for (int r = 0; r < 4; ++r)
                        sm.ep[row + r][col] = (bf16)(acc[im][in][r] + bias);
                }
            }
        }
        __syncthreads();
#pragma unroll
        for (int i = 0; i < 8; ++i) {
            const int c = i * 256 + t;
            const int row = c >> 5, colg = (c & 31) * 8;
            *(uint4*)(O + (size_t)(by * 128 + pph * 64 + row) * EE + bxp * 256 + colg) =
                *(const uint4*)&sm.ep[row][colg];
        }
        __syncthreads();
    }
}

// ---------------------------------------------------------------------------
// Scores: S[m][n] = f16( (Q[m][n] @ K[m][n]^T) * inv_scale ). 128x256 tiles
// (R6 geometry — best measured). Triple-buffered K-loop, raw barrier+vmcnt(6).
// grid flat 1024; XCD swizzle: f&7 owns 4 (map,batch) slices (2 MB each).
// ---------------------------------------------------------------------------
struct ScoresParams {
    const bf16* q[4];
    const bf16* k[4];
    f16* s[4];
};

__global__ __launch_bounds__(256, 2) void scores_kernel(ScoresParams p) {
    const int f = blockIdx.x;
    const int xcd = f & 7;
    const int j = f >> 3;            // 0..127 per XCD
    const int z = (xcd << 2) + (j >> 5);
    const int map = z >> 3, n = z & 7;
    const int tile = j & 31;
    const int bxp = tile & 3, by = tile >> 2;

    const bf16* __restrict__ Qb = p.q[map] + (size_t)n * LL * EE;
    const bf16* __restrict__ Kb = p.k[map] + (size_t)n * LL * EE;
    f16* __restrict__ Sb = p.s[map] + (size_t)n * LL * LL;

    __shared__ union {
        struct { alignas(16) bf16 A[3][128][32]; alignas(16) bf16 B[3][256][32]; } st;
        alignas(16) f16 ep[64][264];
    } sm;

    const int t = threadIdx.x;
    const int lane = t & 63, wid = t >> 6;
    const int wm = wid & 1, wn = wid >> 1;
    const int lr = lane & 15, kg = lane >> 4;

    f32x4 acc[4][8] = {};

    const int srow = t >> 2;
    const int cgl = t & 3;
    const int gcg = (cgl ^ ((srow >> 1) & 3)) * 8;
    const int scg = (kg ^ ((lr >> 1) & 3)) * 8;

    const bf16* Qrow0 = Qb + (size_t)(by * 128 + srow) * EE + gcg;
    const bf16* Krow0 = Kb + (size_t)(bxp * 256 + srow) * EE + gcg;

    auto stage = [&](int k, int b) {
        const int k0 = k * 32;
#pragma unroll
        for (int i = 0; i < 2; ++i)
            GLOAD_LDS16(Qrow0 + (size_t)(64 * i) * EE + k0, &sm.st.A[b][srow + 64 * i][cgl * 8]);
#pragma unroll
        for (int i = 0; i < 4; ++i)
            GLOAD_LDS16(Krow0 + (size_t)(64 * i) * EE + k0, &sm.st.B[b][srow + 64 * i][cgl * 8]);
    };
    auto compute = [&](int b) {
        bf16x8 af[4], bfr[8];
#pragma unroll
        for (int im = 0; im < 4; ++im)
            af[im] = *(const bf16x8*)&sm.st.A[b][wm * 64 + im * 16 + lr][scg];
#pragma unroll
        for (int in = 0; in < 8; ++in)
            bfr[in] = *(const bf16x8*)&sm.st.B[b][wn * 128 + in * 16 + lr][scg];
#pragma unroll
        for (int im = 0; im < 4; ++im)
#pragma unroll
            for (int in = 0; in < 8; ++in)
                acc[im][in] = mfma16(af[im], bfr[in], acc[im][in]);
    };

    stage(0, 0);
    stage(1, 1);
#pragma unroll
    for (int k = 0; k < 16; ++k) {
        if (k < 15) __builtin_amdgcn_s_waitcnt(WAIT_VM6);
        else        __builtin_amdgcn_s_waitcnt(WAIT_VM0);
        wave_barrier();
        if (k < 14) stage(k + 2, (k + 2) % 3);
        compute(k % 3);
    }
    __syncthreads();

    const float inv_scale = 0.011048543456039806f;  // 1/(4*sqrt(512))
#pragma unroll
    for (int pph = 0; pph < 2; ++pph) {
        if (wm == pph) {
#pragma unroll
            for (int im = 0; im < 4; ++im) {
                const int row = im * 16 + kg * 4;
#pragma unroll
                for (int in = 0; in < 8; ++in) {
                    const int col = wn * 128 + in * 16 + lr;
#pragma unroll
                    for (int r = 0; r < 4; ++r)
                        sm.ep[row + r][col] = (f16)(acc[im][in][r] * inv_scale);
                }
            }
        }
        __syncthreads();
#pragma unroll
        for (int i = 0; i < 8; ++i) {
            const int c = i * 256 + t;
            const int row = c >> 5, colg = (c & 31) * 8;
            *(uint4*)(Sb + (size_t)(by * 128 + pph * 64 + row) * LL + bxp * 256 + colg) =
                *(const uint4*)&sm.ep[row][colg];
        }
        __syncthreads();
    }
}

// ---------------------------------------------------------------------------
// Row softmax (1024 cols, f16 in) over 8 batches, mean, write one quadrant.
// No max-subtraction: |S| small (sigma ~0.25), exp is exact-safe in fp32.
// grid (1024, 4): x = q row, y = map.
// ---------------------------------------------------------------------------
struct SmParams {
    const f16* s[4];
};

__global__ __launch_bounds__(256) void softmax_mean_kernel(SmParams p, float* __restrict__ out) {
    const int q = blockIdx.x;
    const int map = blockIdx.y;
    const f16* __restrict__ S = p.s[map];
    const int t = threadIdx.x;
    const int lane = t & 63, wid = t >> 6;
    __shared__ float red[NBATCH][4];

    f16x4 v[NBATCH];
#pragma unroll
    for (int n = 0; n < NBATCH; ++n)
        v[n] = *(const f16x4*)(S + ((size_t)n * LL + q) * LL + t * 4);

    float e[NBATCH][4];
#pragma unroll
    for (int n = 0; n < NBATCH; ++n) {
        float s = 0.f;
#pragma unroll
        for (int j = 0; j < 4; ++j) {
            e[n][j] = __expf((float)v[n][j]);
            s += e[n][j];
        }
#pragma unroll
        for (int off = 32; off; off >>= 1) s += __shfl_xor(s, off);
        if (lane == 0) red[n][wid] = s;
    }
    __syncthreads();

    float acc[4] = {};
#pragma unroll
    for (int n = 0; n < NBATCH; ++n) {
        const float inv = 1.0f / (red[n][0] + red[n][1] + red[n][2] + red[n][3]);
#pragma unroll
        for (int j = 0; j < 4; ++j) acc[j] += e[n][j] * inv;
    }

    const int orow = (map >= 2 ? LL : 0) + q;
    const int ocol = (map & 1 ? LL : 0) + t * 4;
    float4 o = make_float4(acc[0] * 0.125f, acc[1] * 0.125f, acc[2] * 0.125f, acc[3] * 0.125f);
    *(float4*)(out + (size_t)orow * (2 * LL) + ocol) = o;
}

// ---------------------------------------------------------------------------
extern "C" void kernel_launch(void* const* d_in, const int* in_sizes, int n_in,
                              void* d_out, int out_size, void* d_ws, size_t ws_size,
                              hipStream_t stream) {
    const float* modalA = (const float*)d_in[0];
    const float* modalB = (const float*)d_in[1];
    const float* WqA = (const float*)d_in[2];
    const float* bqA = (const float*)d_in[3];
    const float* WkA = (const float*)d_in[4];
    const float* bkA = (const float*)d_in[5];
    const float* WqB = (const float*)d_in[6];
    const float* bqB = (const float*)d_in[7];
    const float* WkB = (const float*)d_in[8];
    const float* bkB = (const float*)d_in[9];
    float* out = (float*)d_out;

    // ws layout (~100.7 MB):
    //   [qk: 4 x 8192x512 bf16 = 33.55 MB]
    //   [region2: XA/XB/W4 bf16 (18.9 MB) then reused by S[4] f16 (67.1 MB)]
    const size_t projN = (size_t)(NBATCH * LL) * EE;       // 4 Mi elems
    const size_t mapN = (size_t)NBATCH * LL * LL;          // 8 Mi elems per map
    char* base = (char*)d_ws;
    bf16* qk = (bf16*)base;
    char* region2 = base + 4 * projN * sizeof(bf16);
    bf16* XA = (bf16*)region2;
    bf16* XB = XA + projN;
    bf16* W4 = XB + projN;                                  // 4 x 512x512
    f16* S = (f16*)region2;

    CvtParams cp;
    cp.src[0] = modalA; cp.dst[0] = XA; cp.n4[0] = (int)(projN / 4);
    cp.src[1] = modalB; cp.dst[1] = XB; cp.n4[1] = (int)(projN / 4);
    const float* wsrc[4] = {WqA, WkA, WqB, WkB};
    for (int i = 0; i < 4; ++i) {
        cp.src[2 + i] = wsrc[i];
        cp.dst[2 + i] = W4 + (size_t)i * EE * EE;
        cp.n4[2 + i] = EE * EE / 4;
    }
    cvt_kernel<<<dim3(512, 6), 256, 0, stream>>>(cp);

    ProjParams pp;
    pp.x[0] = XA; pp.x[1] = XA; pp.x[2] = XB; pp.x[3] = XB;
    for (int i = 0; i < 4; ++i) pp.w[i] = W4 + (size_t)i * EE * EE;
    pp.b[0] = bqA; pp.b[1] = bkA; pp.b[2] = bqB; pp.b[3] = bkB;
    proj_kernel<<<dim3(512), 256, 0, stream>>>(pp, qk);

    const bf16* qA = qk + 0 * projN;
    const bf16* kA = qk + 1 * projN;
    const bf16* qB = qk + 2 * projN;
    const bf16* kB = qk + 3 * projN;

    // map order: 0=(qA,kA)->TL, 1=(qA,kB)->TR, 2=(qB,kB)->BL, 3=(qB,kA)->BR
    ScoresParams sp;
    sp.q[0] = qA; sp.q[1] = qA; sp.q[2] = qB; sp.q[3] = qB;
    sp.k[0] = kA; sp.k[1] = kB; sp.k[2] = kB; sp.k[3] = kA;
    for (int m = 0; m < 4; ++m) sp.s[m] = S + (size_t)m * mapN;
    scores_kernel<<<dim3(1024), 256, 0, stream>>>(sp);

    SmParams smp;
    for (int m = 0; m < 4; ++m) smp.s[m] = S + (size_t)m * mapN;
    softmax_mean_kernel<<<dim3(1024, 4), 256, 0, stream>>>(smp, out);
}